// Round 1
// baseline (448.603 us; speedup 1.0000x reference)
//
#include <hip/hip_runtime.h>
#include <hip/hip_bf16.h>

// Problem constants (fixed by the reference: N=8192, DIM=64, T_ITERS=4).
// T controls the number of host-side kernel launches and is only available
// device-side, so it is hardcoded to the problem's T_ITERS=4.
#define NN 8192
#define DIM 64
#define T_IT 4

// ---------------------------------------------------------------------------
// Kernel 1: per-row relu-sums of graph. s_pos[i] = sum_j max(g,0),
// s_neg[i] = sum_j max(-g,0). One block per row, 256 threads, float4 loads.
// This is the bandwidth-dominant kernel (256 MB read).
// ---------------------------------------------------------------------------
__global__ __launch_bounds__(256) void rowsum_kernel(
    const float* __restrict__ graph,
    float* __restrict__ s_pos, float* __restrict__ s_neg) {
  const int row = blockIdx.x;
  const int t = threadIdx.x;
  const float4* g = (const float4*)(graph + (size_t)row * NN);
  float sp = 0.f, sn = 0.f;
#pragma unroll
  for (int it = 0; it < NN / 4 / 256; ++it) {  // 8 iterations
    float4 v = g[t + it * 256];
    sp += fmaxf(v.x, 0.f) + fmaxf(v.y, 0.f) + fmaxf(v.z, 0.f) + fmaxf(v.w, 0.f);
    sn += fmaxf(-v.x, 0.f) + fmaxf(-v.y, 0.f) + fmaxf(-v.z, 0.f) + fmaxf(-v.w, 0.f);
  }
  // wave (64-lane) reduction
  for (int off = 32; off > 0; off >>= 1) {
    sp += __shfl_down(sp, off);
    sn += __shfl_down(sn, off);
  }
  __shared__ float lds[2][4];
  const int wave = t >> 6;
  if ((t & 63) == 0) { lds[0][wave] = sp; lds[1][wave] = sn; }
  __syncthreads();
  if (t == 0) {
    s_pos[row] = lds[0][0] + lds[0][1] + lds[0][2] + lds[0][3];
    s_neg[row] = lds[1][0] + lds[1][1] + lds[1][2] + lds[1][3];
  }
}

// ---------------------------------------------------------------------------
// Kernel 2: tiny prep. p[d] = sum_k relu(t4[k]) * theta3[k][d],
//                      q[d] = sum_k relu(-t4[k]) * theta3[k][d].
// ---------------------------------------------------------------------------
__global__ void prep_kernel(const float* __restrict__ theta3,
                            const float* __restrict__ theta4,
                            float* __restrict__ pq) {
  const int d = threadIdx.x;  // 64 threads
  float p = 0.f, q = 0.f;
  for (int k = 0; k < DIM; ++k) {
    const float t4 = theta4[k];
    const float th = theta3[k * DIM + d];
    p += fmaxf(t4, 0.f) * th;
    q += fmaxf(-t4, 0.f) * th;
  }
  pq[d] = p;
  pq[DIM + d] = q;
}

// ---------------------------------------------------------------------------
// Kernel 3: one scan step.
//   u_new[i][d] = relu( x[i]*theta1[d] + s_pos[i]*p[d] + s_neg[i]*q[d]
//                       + (summ_in @ theta2)[d] - (u[i] @ theta2)[d] )
// and accumulates summ_out[d] = sum_i u_new[i][d] via per-block atomics.
// Block = 256 threads = 4 rows x 64 dims. theta2 staged in LDS.
// In-place u update is safe: each row is read+written only by its own block.
// ---------------------------------------------------------------------------
__global__ __launch_bounds__(256) void update_kernel(
    const float* __restrict__ theta1, const float* __restrict__ theta2,
    const int* __restrict__ x, const float* __restrict__ s_pos,
    const float* __restrict__ s_neg, const float* __restrict__ pq,
    const float* __restrict__ summ_in, float* __restrict__ summ_out,
    float* __restrict__ u) {
  __shared__ float th2[DIM * DIM];  // 16 KB
  __shared__ float gsh[DIM];
  __shared__ float ush[4][DIM];
  __shared__ float red[4][DIM];
  const int t = threadIdx.x;
  const int d = t & 63;
  const int r = t >> 6;  // row-within-group 0..3

  for (int i = t; i < DIM * DIM; i += 256) th2[i] = theta2[i];
  __syncthreads();
  if (t < DIM) {
    float g = 0.f;
    for (int k = 0; k < DIM; ++k) g += summ_in[k] * th2[k * DIM + d];
    gsh[d] = g;
  }
  const float pd = pq[d];
  const float qd = pq[DIM + d];
  const float t1d = theta1[d];
  __syncthreads();
  const float gd = gsh[d];

  float acc = 0.f;
  for (int base = blockIdx.x * 4; base < NN; base += gridDim.x * 4) {
    const int row = base + r;
    ush[r][d] = u[(size_t)row * DIM + d];
    __syncthreads();
    float dot = 0.f;
#pragma unroll
    for (int k = 0; k < DIM; ++k) dot += ush[r][k] * th2[k * DIM + d];
    float val = (float)x[row] * t1d + s_pos[row] * pd + s_neg[row] * qd + gd - dot;
    val = fmaxf(val, 0.f);
    u[(size_t)row * DIM + d] = val;
    acc += val;
    __syncthreads();  // protect ush before next iteration's overwrite
  }
  red[r][d] = acc;
  __syncthreads();
  if (r == 0) {
    const float s = red[0][d] + red[1][d] + red[2][d] + red[3][d];
    atomicAdd(&summ_out[d], s);
  }
}

// ---------------------------------------------------------------------------
// Kernel 4: readout. out = relu(concat(summ@theta6, u[v]@theta7)) @ theta5.
// Single block, 128 threads.
// ---------------------------------------------------------------------------
__global__ void final_kernel(const float* __restrict__ theta5,
                             const float* __restrict__ theta6,
                             const float* __restrict__ theta7,
                             const float* __restrict__ summ,
                             const float* __restrict__ u,
                             const int* __restrict__ vptr,
                             float* __restrict__ out) {
  const int t = threadIdx.x;  // 128 threads
  const int d = t & 63;
  float h;
  if (t < DIM) {
    float s = 0.f;
    for (int k = 0; k < DIM; ++k) s += summ[k] * theta6[k * DIM + d];
    h = fmaxf(s, 0.f) * theta5[d];
  } else {
    const int v = *vptr;
    const float* uv = u + (size_t)v * DIM;
    float s = 0.f;
    for (int k = 0; k < DIM; ++k) s += uv[k] * theta7[k * DIM + d];
    h = fmaxf(s, 0.f) * theta5[DIM + d];
  }
  __shared__ float red[128];
  red[t] = h;
  __syncthreads();
  if (t == 0) {
    float s = 0.f;
    for (int i = 0; i < 128; ++i) s += red[i];
    out[0] = s;
  }
}

extern "C" void kernel_launch(void* const* d_in, const int* in_sizes, int n_in,
                              void* d_out, int out_size, void* d_ws, size_t ws_size,
                              hipStream_t stream) {
  const float* graph  = (const float*)d_in[0];
  const int*   x      = (const int*)d_in[1];
  const float* theta1 = (const float*)d_in[2];
  const float* theta2 = (const float*)d_in[3];
  const float* theta3 = (const float*)d_in[4];
  const float* theta4 = (const float*)d_in[5];
  const float* theta5 = (const float*)d_in[6];
  const float* theta6 = (const float*)d_in[7];
  const float* theta7 = (const float*)d_in[8];
  const int*   vptr   = (const int*)d_in[9];
  // d_in[10] = T (device-side; hardcoded T_IT=4 per problem definition)
  float* out = (float*)d_out;

  // Workspace layout (floats):
  //   s_pos : [0, NN)
  //   s_neg : [NN, 2NN)
  //   pq    : [2NN, 2NN+128)
  //   summ  : [2NN+128, 2NN+448)   -- (T_IT+1) x 64, must start zeroed
  //   u     : [2NN+448, 2NN+448+NN*64)  -- must start zeroed (u0 = 0)
  float* ws    = (float*)d_ws;
  float* s_pos = ws;
  float* s_neg = ws + NN;
  float* pq    = ws + 2 * NN;
  float* summ  = ws + 2 * NN + 128;
  float* u     = ws + 2 * NN + 448;

  // Zero summ buffers + u state (ws is re-poisoned to 0xAA before each call).
  const size_t zero_off_bytes = (size_t)(2 * NN + 128) * sizeof(float);
  const size_t zero_len_bytes = (size_t)(320 + (size_t)NN * DIM) * sizeof(float);
  hipMemsetAsync((char*)d_ws + zero_off_bytes, 0, zero_len_bytes, stream);

  rowsum_kernel<<<NN, 256, 0, stream>>>(graph, s_pos, s_neg);
  prep_kernel<<<1, DIM, 0, stream>>>(theta3, theta4, pq);
  for (int t = 0; t < T_IT; ++t) {
    update_kernel<<<256, 256, 0, stream>>>(theta1, theta2, x, s_pos, s_neg, pq,
                                           summ + t * DIM, summ + (t + 1) * DIM, u);
  }
  final_kernel<<<1, 128, 0, stream>>>(theta5, theta6, theta7,
                                      summ + T_IT * DIM, u, vptr, out);
}

// Round 2
// 431.262 us; speedup vs baseline: 1.0402x; 1.0402x over previous
//
#include <hip/hip_runtime.h>

// Problem constants (fixed by the reference: N=8192, DIM=64, T_ITERS=4).
// T is only available device-side; it controls host launch count, so it is
// hardcoded to the problem's T_ITERS=4.
#define NN 8192
#define DIM 64
#define T_IT 4

// ---------------------------------------------------------------------------
// Kernel 1: prep. p[d] = sum_k relu(t4[k])*theta3[k][d],
//                 q[d] = sum_k relu(-t4[k])*theta3[k][d].
// Also zeroes the summ accumulators (T_IT x 64 floats) so no memsetAsync is
// needed (ws is poisoned to 0xAA before every call).
// ---------------------------------------------------------------------------
__global__ void prep_kernel(const float* __restrict__ theta3,
                            const float* __restrict__ theta4,
                            float* __restrict__ pq,
                            float* __restrict__ summ) {
  const int d = threadIdx.x;  // 64 threads
  float p = 0.f, q = 0.f;
  for (int k = 0; k < DIM; ++k) {
    const float t4 = theta4[k];
    const float th = theta3[k * DIM + d];
    p += fmaxf(t4, 0.f) * th;
    q += fmaxf(-t4, 0.f) * th;
  }
  pq[d] = p;
  pq[DIM + d] = q;
#pragma unroll
  for (int t = 0; t < T_IT; ++t) summ[t * DIM + d] = 0.f;
}

// ---------------------------------------------------------------------------
// Kernel 2 (the BW-dominant one, 256 MB read): fused rowsum + scan step 1.
// Since u0 = 0 and summ0 = 0, step 1 collapses to u1 = relu(a + c):
//   sp[i] = sum_j max(g[i,j],0), sn[i] = sum_j max(-g[i,j],0)
//   u1[i][d] = relu(x_i*theta1[d] + sp_i*p[d] + sn_i*q[d])
// One wave per row (4 rows in flight per 256-thread block), 512 blocks,
// 4 rows per wave via grid stride. Emits s_pos/s_neg (for later steps'
// a+c recompute), u1, and summ1 (block-partial -> 64 atomics/block).
// ---------------------------------------------------------------------------
__global__ __launch_bounds__(256) void fused_rowsum_step1(
    const float* __restrict__ graph, const int* __restrict__ x,
    const float* __restrict__ theta1, const float* __restrict__ pq,
    float* __restrict__ s_pos, float* __restrict__ s_neg,
    float* __restrict__ u, float* __restrict__ summ1) {
  const int wave = threadIdx.x >> 6;
  const int lane = threadIdx.x & 63;
  const float pd = pq[lane];
  const float qd = pq[DIM + lane];
  const float t1d = theta1[lane];
  float accd = 0.f;  // per-lane partial of summ1[lane]

  for (int row = blockIdx.x * 4 + wave; row < NN; row += 2048) {
    const float4* g = (const float4*)(graph + (size_t)row * NN);
    float sp = 0.f, sn = 0.f;
    for (int it = 0; it < NN / 4 / 64; it += 8) {  // 32 iters, unrolled by 8
#pragma unroll
      for (int j = 0; j < 8; ++j) {
        const float4 v = g[lane + (it + j) * 64];
        sp += fmaxf(v.x, 0.f) + fmaxf(v.y, 0.f) + fmaxf(v.z, 0.f) + fmaxf(v.w, 0.f);
        sn += fmaxf(-v.x, 0.f) + fmaxf(-v.y, 0.f) + fmaxf(-v.z, 0.f) + fmaxf(-v.w, 0.f);
      }
    }
#pragma unroll
    for (int off = 32; off > 0; off >>= 1) {
      sp += __shfl_down(sp, off);
      sn += __shfl_down(sn, off);
    }
    sp = __shfl(sp, 0);
    sn = __shfl(sn, 0);
    if (lane == 0) {
      s_pos[row] = sp;
      s_neg[row] = sn;
    }
    const float acv = (float)x[row] * t1d + sp * pd + sn * qd;
    const float uv = fmaxf(acv, 0.f);
    u[(size_t)row * DIM + lane] = uv;
    accd += uv;
  }

  __shared__ float red[4][DIM];
  red[wave][lane] = accd;
  __syncthreads();
  if (wave == 0)
    atomicAdd(&summ1[lane],
              red[0][lane] + red[1][lane] + red[2][lane] + red[3][lane]);
}

// ---------------------------------------------------------------------------
// Kernel 3: scan steps 2..T.
//   u_new[i][d] = relu( acv[i][d] + (summ_in @ th2)[d] - (u[i] @ th2)[d] )
// with acv recomputed from x/s_pos/s_neg (broadcast scalars, saves a 2 MB
// ac array). theta2 staged in LDS; u-row dot via float4 LDS broadcasts.
// 256 blocks x 256 threads = 4 rows x 64 dims per iter, 8 iters/block.
// In-place u update is safe (each row touched by exactly one block).
// ---------------------------------------------------------------------------
__global__ __launch_bounds__(256) void step_kernel(
    const float* __restrict__ theta1, const float* __restrict__ theta2,
    const int* __restrict__ x, const float* __restrict__ s_pos,
    const float* __restrict__ s_neg, const float* __restrict__ pq,
    const float* __restrict__ summ_in, float* __restrict__ summ_out,
    float* __restrict__ u) {
  __shared__ float th2[DIM * DIM];  // 16 KB
  __shared__ float gsh[DIM];
  __shared__ __align__(16) float ush[4][DIM];
  __shared__ float red[4][DIM];
  const int t = threadIdx.x;
  const int d = t & 63;
  const int r = t >> 6;  // row-within-group 0..3

  for (int i = t; i < DIM * DIM; i += 256) th2[i] = theta2[i];
  __syncthreads();
  if (t < DIM) {
    float g = 0.f;
    for (int k = 0; k < DIM; ++k) g += summ_in[k] * th2[k * DIM + d];
    gsh[d] = g;
  }
  const float pd = pq[d];
  const float qd = pq[DIM + d];
  const float t1d = theta1[d];
  __syncthreads();
  const float gd = gsh[d];

  float acc = 0.f;
  for (int base = blockIdx.x * 4; base < NN; base += gridDim.x * 4) {
    const int row = base + r;
    ush[r][d] = u[(size_t)row * DIM + d];
    __syncthreads();
    float dot = 0.f;
    const float4* ur = (const float4*)ush[r];
#pragma unroll
    for (int kk = 0; kk < DIM / 4; ++kk) {
      const float4 uv = ur[kk];
      dot += uv.x * th2[(4 * kk + 0) * DIM + d];
      dot += uv.y * th2[(4 * kk + 1) * DIM + d];
      dot += uv.z * th2[(4 * kk + 2) * DIM + d];
      dot += uv.w * th2[(4 * kk + 3) * DIM + d];
    }
    const float acv = (float)x[row] * t1d + s_pos[row] * pd + s_neg[row] * qd;
    float val = fmaxf(acv + gd - dot, 0.f);
    u[(size_t)row * DIM + d] = val;
    acc += val;
    __syncthreads();  // protect ush before next iteration's overwrite
  }
  red[r][d] = acc;
  __syncthreads();
  if (r == 0) {
    atomicAdd(&summ_out[d], red[0][d] + red[1][d] + red[2][d] + red[3][d]);
  }
}

// ---------------------------------------------------------------------------
// Kernel 4: readout. out = relu(concat(summ@theta6, u[v]@theta7)) @ theta5.
// ---------------------------------------------------------------------------
__global__ void final_kernel(const float* __restrict__ theta5,
                             const float* __restrict__ theta6,
                             const float* __restrict__ theta7,
                             const float* __restrict__ summ,
                             const float* __restrict__ u,
                             const int* __restrict__ vptr,
                             float* __restrict__ out) {
  const int t = threadIdx.x;  // 128 threads
  const int d = t & 63;
  float h;
  if (t < DIM) {
    float s = 0.f;
    for (int k = 0; k < DIM; ++k) s += summ[k] * theta6[k * DIM + d];
    h = fmaxf(s, 0.f) * theta5[d];
  } else {
    const int v = *vptr;
    const float* uv = u + (size_t)v * DIM;
    float s = 0.f;
    for (int k = 0; k < DIM; ++k) s += uv[k] * theta7[k * DIM + d];
    h = fmaxf(s, 0.f) * theta5[DIM + d];
  }
  __shared__ float red[128];
  red[t] = h;
  __syncthreads();
  if (t == 0) {
    float s = 0.f;
    for (int i = 0; i < 128; ++i) s += red[i];
    out[0] = s;
  }
}

extern "C" void kernel_launch(void* const* d_in, const int* in_sizes, int n_in,
                              void* d_out, int out_size, void* d_ws, size_t ws_size,
                              hipStream_t stream) {
  const float* graph  = (const float*)d_in[0];
  const int*   x      = (const int*)d_in[1];
  const float* theta1 = (const float*)d_in[2];
  const float* theta2 = (const float*)d_in[3];
  const float* theta3 = (const float*)d_in[4];
  const float* theta4 = (const float*)d_in[5];
  const float* theta5 = (const float*)d_in[6];
  const float* theta6 = (const float*)d_in[7];
  const float* theta7 = (const float*)d_in[8];
  const int*   vptr   = (const int*)d_in[9];
  // d_in[10] = T (device-side; hardcoded T_IT=4 per problem definition)
  float* out = (float*)d_out;

  // Workspace layout (floats):
  //   pq    : [0, 128)
  //   summ  : [128, 128 + T_IT*64)        -- summ[t] = sum over rows of u_{t+1}
  //   s_pos : [384, 384+NN)
  //   s_neg : [384+NN, 384+2NN)
  //   u     : [384+2NN, 384+2NN+NN*DIM)
  // No memset needed: prep zeroes summ; s_pos/s_neg/u are fully written by
  // fused_rowsum_step1 before anything reads them.
  float* ws    = (float*)d_ws;
  float* pq    = ws;
  float* summ  = ws + 128;
  float* s_pos = ws + 128 + T_IT * DIM;
  float* s_neg = s_pos + NN;
  float* u     = s_neg + NN;

  prep_kernel<<<1, DIM, 0, stream>>>(theta3, theta4, pq, summ);
  fused_rowsum_step1<<<512, 256, 0, stream>>>(graph, x, theta1, pq,
                                              s_pos, s_neg, u, summ);
  for (int t = 1; t < T_IT; ++t) {
    step_kernel<<<256, 256, 0, stream>>>(theta1, theta2, x, s_pos, s_neg, pq,
                                         summ + (t - 1) * DIM, summ + t * DIM, u);
  }
  final_kernel<<<1, 128, 0, stream>>>(theta5, theta6, theta7,
                                      summ + (T_IT - 1) * DIM, u, vptr, out);
}

// Round 4
// 408.936 us; speedup vs baseline: 1.0970x; 1.0546x over previous
//
#include <hip/hip_runtime.h>

// Problem constants (fixed by the reference: N=8192, DIM=64, T_ITERS=4).
// T is only available device-side; it controls host launch count, so it is
// hardcoded to the problem's T_ITERS=4.
#define NN 8192
#define DIM 64
#define T_IT 4
#define NPART 8  // spread copies for summ1 atomic accumulation

// Native vector type for __builtin_nontemporal_load (HIP_vector_type is a
// struct and is rejected by the builtin; ext_vector_type is accepted).
typedef float nfloat4 __attribute__((ext_vector_type(4)));

// ---------------------------------------------------------------------------
// Kernel 1: prep. p[d] = sum_k relu(t4[k])*theta3[k][d],
//                 q[d] = sum_k relu(-t4[k])*theta3[k][d].
// Also zeroes the summ slots (3 x 64 for summ2..summ4) and the 8 spread
// copies of summ1 (ws is poisoned to 0xAA before every call).
// ---------------------------------------------------------------------------
__global__ void prep_kernel(const float* __restrict__ theta3,
                            const float* __restrict__ theta4,
                            float* __restrict__ pq,
                            float* __restrict__ summ1_parts,
                            float* __restrict__ summ) {
  const int d = threadIdx.x;  // 64 threads
  float p = 0.f, q = 0.f;
  for (int k = 0; k < DIM; ++k) {
    const float t4 = theta4[k];
    const float th = theta3[k * DIM + d];
    p += fmaxf(t4, 0.f) * th;
    q += fmaxf(-t4, 0.f) * th;
  }
  pq[d] = p;
  pq[DIM + d] = q;
#pragma unroll
  for (int c = 0; c < NPART; ++c) summ1_parts[c * DIM + d] = 0.f;
#pragma unroll
  for (int t = 0; t < T_IT - 1; ++t) summ[t * DIM + d] = 0.f;
}

// ---------------------------------------------------------------------------
// Kernel 2 (BW-dominant, 256 MB read): fused rowsum + scan step 1.
// Since u0 = 0 and summ0 = 0, step 1 collapses to u1 = relu(a + c):
//   sp[i] = sum_j max(g[i,j],0), sn[i] = sum_j max(-g[i,j],0)
//   u1[i][d] = relu(x_i*theta1[d] + sp_i*p[d] + sn_i*q[d])
// 2048 blocks x 256 threads = 8192 waves, EXACTLY one row per wave
// (8 blocks/CU, up to 32 waves/CU for deep HBM request queues).
// Graph is read-once -> nontemporal loads (don't pollute L2).
// summ1 accumulated into 8 spread copies to cut atomic contention
// (2048 wave-atomics / 8 copies = 256-deep per address).
// ---------------------------------------------------------------------------
__global__ __launch_bounds__(256) void fused_rowsum_step1(
    const float* __restrict__ graph, const int* __restrict__ x,
    const float* __restrict__ theta1, const float* __restrict__ pq,
    float* __restrict__ s_pos, float* __restrict__ s_neg,
    float* __restrict__ u, float* __restrict__ summ1_parts) {
  const int wave = threadIdx.x >> 6;
  const int lane = threadIdx.x & 63;
  const int row = blockIdx.x * 4 + wave;  // 2048*4 == 8192 == NN
  const float pd = pq[lane];
  const float qd = pq[DIM + lane];
  const float t1d = theta1[lane];

  const nfloat4* g = (const nfloat4*)(graph + (size_t)row * NN);
  float sp = 0.f, sn = 0.f;
  for (int it = 0; it < NN / 4 / 64; it += 8) {  // 32 iters, 8 loads in flight
#pragma unroll
    for (int j = 0; j < 8; ++j) {
      const nfloat4 v = __builtin_nontemporal_load(&g[lane + (it + j) * 64]);
      sp += fmaxf(v.x, 0.f) + fmaxf(v.y, 0.f) + fmaxf(v.z, 0.f) + fmaxf(v.w, 0.f);
      sn += fmaxf(-v.x, 0.f) + fmaxf(-v.y, 0.f) + fmaxf(-v.z, 0.f) + fmaxf(-v.w, 0.f);
    }
  }
#pragma unroll
  for (int off = 32; off > 0; off >>= 1) {
    sp += __shfl_down(sp, off);
    sn += __shfl_down(sn, off);
  }
  sp = __shfl(sp, 0);
  sn = __shfl(sn, 0);
  if (lane == 0) {
    s_pos[row] = sp;
    s_neg[row] = sn;
  }
  const float uv = fmaxf((float)x[row] * t1d + sp * pd + sn * qd, 0.f);
  u[(size_t)row * DIM + lane] = uv;

  // block-partial of summ1, one wave-atomic per block into a spread copy
  __shared__ float red[4][DIM];
  red[wave][lane] = uv;
  __syncthreads();
  if (wave == 0)
    atomicAdd(&summ1_parts[(blockIdx.x & (NPART - 1)) * DIM + lane],
              red[0][lane] + red[1][lane] + red[2][lane] + red[3][lane]);
}

// ---------------------------------------------------------------------------
// Kernel 3: scan steps 2..T.
//   u_new[i][d] = relu( acv[i][d] + (summ_in @ th2)[d] - (u[i] @ th2)[d] )
// summ_in is the sum of `ncopies` 64-float copies (8 for step 2, 1 after).
// theta2 staged in LDS; u-row dot via float4 LDS broadcasts.
// 256 blocks x 256 threads = 4 rows x 64 dims per iter, 8 iters/block.
// In-place u update is safe (each row touched by exactly one block).
// ---------------------------------------------------------------------------
__global__ __launch_bounds__(256) void step_kernel(
    const float* __restrict__ theta1, const float* __restrict__ theta2,
    const int* __restrict__ x, const float* __restrict__ s_pos,
    const float* __restrict__ s_neg, const float* __restrict__ pq,
    const float* __restrict__ summ_in, int ncopies,
    float* __restrict__ summ_out, float* __restrict__ u) {
  __shared__ float th2[DIM * DIM];  // 16 KB
  __shared__ float sin_sh[DIM];
  __shared__ float gsh[DIM];
  __shared__ __align__(16) float ush[4][DIM];
  __shared__ float red[4][DIM];
  const int t = threadIdx.x;
  const int d = t & 63;
  const int r = t >> 6;  // row-within-group 0..3

  for (int i = t; i < DIM * DIM; i += 256) th2[i] = theta2[i];
  if (t < DIM) {
    float s = 0.f;
    for (int c = 0; c < ncopies; ++c) s += summ_in[c * DIM + t];
    sin_sh[t] = s;
  }
  __syncthreads();
  if (t < DIM) {
    float g = 0.f;
    for (int k = 0; k < DIM; ++k) g += sin_sh[k] * th2[k * DIM + d];
    gsh[d] = g;
  }
  const float pd = pq[d];
  const float qd = pq[DIM + d];
  const float t1d = theta1[d];
  __syncthreads();
  const float gd = gsh[d];

  float acc = 0.f;
  for (int base = blockIdx.x * 4; base < NN; base += gridDim.x * 4) {
    const int row = base + r;
    ush[r][d] = u[(size_t)row * DIM + d];
    __syncthreads();
    float dot = 0.f;
    const float4* ur = (const float4*)ush[r];
#pragma unroll
    for (int kk = 0; kk < DIM / 4; ++kk) {
      const float4 uv = ur[kk];
      dot += uv.x * th2[(4 * kk + 0) * DIM + d];
      dot += uv.y * th2[(4 * kk + 1) * DIM + d];
      dot += uv.z * th2[(4 * kk + 2) * DIM + d];
      dot += uv.w * th2[(4 * kk + 3) * DIM + d];
    }
    const float acv = (float)x[row] * t1d + s_pos[row] * pd + s_neg[row] * qd;
    float val = fmaxf(acv + gd - dot, 0.f);
    u[(size_t)row * DIM + d] = val;
    acc += val;
    __syncthreads();  // protect ush before next iteration's overwrite
  }
  red[r][d] = acc;
  __syncthreads();
  if (r == 0) {
    atomicAdd(&summ_out[d], red[0][d] + red[1][d] + red[2][d] + red[3][d]);
  }
}

// ---------------------------------------------------------------------------
// Kernel 4: readout. out = relu(concat(summ@theta6, u[v]@theta7)) @ theta5.
// ---------------------------------------------------------------------------
__global__ void final_kernel(const float* __restrict__ theta5,
                             const float* __restrict__ theta6,
                             const float* __restrict__ theta7,
                             const float* __restrict__ summ,
                             const float* __restrict__ u,
                             const int* __restrict__ vptr,
                             float* __restrict__ out) {
  const int t = threadIdx.x;  // 128 threads
  const int d = t & 63;
  float h;
  if (t < DIM) {
    float s = 0.f;
    for (int k = 0; k < DIM; ++k) s += summ[k] * theta6[k * DIM + d];
    h = fmaxf(s, 0.f) * theta5[d];
  } else {
    const int v = *vptr;
    const float* uv = u + (size_t)v * DIM;
    float s = 0.f;
    for (int k = 0; k < DIM; ++k) s += uv[k] * theta7[k * DIM + d];
    h = fmaxf(s, 0.f) * theta5[DIM + d];
  }
  __shared__ float red[128];
  red[t] = h;
  __syncthreads();
  if (t == 0) {
    float s = 0.f;
    for (int i = 0; i < 128; ++i) s += red[i];
    out[0] = s;
  }
}

extern "C" void kernel_launch(void* const* d_in, const int* in_sizes, int n_in,
                              void* d_out, int out_size, void* d_ws, size_t ws_size,
                              hipStream_t stream) {
  const float* graph  = (const float*)d_in[0];
  const int*   x      = (const int*)d_in[1];
  const float* theta1 = (const float*)d_in[2];
  const float* theta2 = (const float*)d_in[3];
  const float* theta3 = (const float*)d_in[4];
  const float* theta4 = (const float*)d_in[5];
  const float* theta5 = (const float*)d_in[6];
  const float* theta6 = (const float*)d_in[7];
  const float* theta7 = (const float*)d_in[8];
  const int*   vptr   = (const int*)d_in[9];
  // d_in[10] = T (device-side; hardcoded T_IT=4 per problem definition)
  float* out = (float*)d_out;

  // Workspace layout (floats):
  //   pq          : [0, 128)
  //   summ1_parts : [128, 128 + 8*64)        -- 8 spread copies of summ1
  //   summ        : [640, 640 + 3*64)        -- summ2..summ4
  //   s_pos       : [832, 832+NN)
  //   s_neg       : [832+NN, 832+2NN)
  //   u           : [832+2NN, 832+2NN+NN*DIM)
  // No memset needed: prep zeroes summ1_parts/summ; s_pos/s_neg/u are fully
  // written by fused_rowsum_step1 before anything reads them.
  float* ws     = (float*)d_ws;
  float* pq     = ws;
  float* parts  = ws + 128;
  float* summ   = ws + 128 + NPART * DIM;
  float* s_pos  = summ + (T_IT - 1) * DIM;
  float* s_neg  = s_pos + NN;
  float* u      = s_neg + NN;

  prep_kernel<<<1, DIM, 0, stream>>>(theta3, theta4, pq, parts, summ);
  fused_rowsum_step1<<<2048, 256, 0, stream>>>(graph, x, theta1, pq,
                                               s_pos, s_neg, u, parts);
  // step 2 folds the 8 spread copies of summ1; steps 3..4 read a single copy
  step_kernel<<<256, 256, 0, stream>>>(theta1, theta2, x, s_pos, s_neg, pq,
                                       parts, NPART, summ + 0 * DIM, u);
  for (int t = 2; t < T_IT; ++t) {
    step_kernel<<<256, 256, 0, stream>>>(theta1, theta2, x, s_pos, s_neg, pq,
                                         summ + (t - 2) * DIM, 1,
                                         summ + (t - 1) * DIM, u);
  }
  final_kernel<<<1, 128, 0, stream>>>(theta5, theta6, theta7,
                                      summ + (T_IT - 2) * DIM, u, vptr, out);
}